// Round 11
// baseline (1485.887 us; speedup 1.0000x reference)
//
#include <hip/hip_runtime.h>

// VQ codebook: z_e (16,256,32,32) f32, codebook (8192,256) f32.
// out f32: z_q_st[4194304] | loss[1] | codes[16384].
// n = b*1024+hw; z_flat[n][d] = z_e[b*262144 + d*1024 + hw]
// Reference: dist = fl32(zz - 2*dot), dot = sequential f32 FMA chain d=0..255,
// argmin ties -> lowest index (validated bitwise in round 2).
//
// Round-11: (a) candidates now carry their SCREEN SCORE; select computes the
// global screen max from stored scores and exactly rescores only candidates
// within MRG of it (~1.5/row) -- kills r10's 687us candidate-gather select.
// (b) screen: KS=2 (512 blocks x 4096 codes), double-buffered 2x32KB LDS with
// loads issued before compute (one barrier/tile, m97 overlap pattern),
// 2 blocks/CU. Block-local LDS threshold, no device atomics in loop.

#define CAP 48        // global per-row candidate cap (pairs)
#define LCAP 24       // per-block LDS candidate cap per row
#define MRG_C 1.96e-4f // dot-domain: 1.5*max ulp(zz) + 2*bf16 screen err bound

typedef short bf16x8 __attribute__((ext_vector_type(8)));
typedef float f32x16 __attribute__((ext_vector_type(16)));

__device__ __forceinline__ unsigned short f2bf(float f) {
    unsigned u = __float_as_uint(f);
    return (unsigned short)((u + 0x7fffu + ((u >> 16) & 1u)) >> 16);
}
// monotone float<->uint key (total order matches float order)
__device__ __forceinline__ unsigned fkey(float f) {
    unsigned u = __float_as_uint(f);
    return (u & 0x80000000u) ? ~u : (u | 0x80000000u);
}
__device__ __forceinline__ float funkey(unsigned k) {
    unsigned u = (k & 0x80000000u) ? (k ^ 0x80000000u) : ~k;
    return __uint_as_float(u);
}
__device__ __forceinline__ void gload_lds16(const void* g, void* l) {
    __builtin_amdgcn_global_load_lds(
        (const __attribute__((address_space(1))) void*)g,
        (__attribute__((address_space(3))) void*)l, 16, 0, 0);
}

// ---- ws byte layout (big path); WS_NEED kept <= 19,070,976 (known-good) ----
#define ZN_B      0u          // f32[16384]
#define CNT_B     65536u      // u32[16384]
#define CAND_B    131072u     // i32[16384*CAP] = 3 MB
#define CANDSC_B  3276800u    // f32[16384*CAP] = 3 MB
#define ZH_B      6422528u    // bf16[16384][256] = 8 MB
#define CH_B      14811136u   // bf16[8192][256] = 4 MB
#define WS_NEED   19005440u

// ---------------- prep: z norms + bf16 transpose (fused) ----------------
__global__ __launch_bounds__(256)
void prep_z_kernel(const float* __restrict__ z, float* __restrict__ zn,
                   unsigned short* __restrict__ zh) {
    __shared__ float zs[64][257];
    const int tid = threadIdx.x;
    const int nbase = blockIdx.x * 64;
    const int b = nbase >> 10, hw0 = nbase & 1023;
    const int lane = tid & 63;
    const int w = tid >> 6;
#pragma unroll 8
    for (int it = 0; it < 64; ++it) {
        int d = it * 4 + w;
        zs[lane][d] = z[(size_t)b * 262144 + (size_t)d * 1024 + hw0 + lane];
    }
    __syncthreads();
    if (tid < 64) {
        float s = 0.f;
        for (int d = 0; d < 256; ++d) {
            float v = zs[tid][d];
            s += v * v;
        }
        zn[nbase + tid] = s;
    }
#pragma unroll 4
    for (int it = 0; it < 16; ++it) {
        int idx = it * 256 + tid;
        int row = idx >> 6;
        int d4 = idx & 63;
        ushort4 hv;
        hv.x = f2bf(zs[row][d4 * 4 + 0]);
        hv.y = f2bf(zs[row][d4 * 4 + 1]);
        hv.z = f2bf(zs[row][d4 * 4 + 2]);
        hv.w = f2bf(zs[row][d4 * 4 + 3]);
        ((ushort4*)(zh + (size_t)(nbase + row) * 256))[d4] = hv;
    }
}

// ---------------- prep: codebook -> bf16 ----------------
__global__ __launch_bounds__(256)
void split_c_kernel(const float* __restrict__ cb, unsigned short* __restrict__ ch) {
    int gid = blockIdx.x * 256 + threadIdx.x;     // float4 index; 524288 total
    float4 v = ((const float4*)cb)[gid];
    ushort4 hv;
    hv.x = f2bf(v.x); hv.y = f2bf(v.y); hv.z = f2bf(v.z); hv.w = f2bf(v.w);
    ((ushort4*)ch)[gid] = hv;
}

// ---------------- screening GEMM (32x32x16, double-buffered) ----------------
// grid (256 row-tiles, 2 k-splits) x 256 thr (4 waves = 2 rg x 2 cq).
// Block: 64 rows x 4096 codes in 64 tiles of 64 codes; 2x32KB LDS ping-pong,
// next tile's global_load_lds issued before compute (one barrier per tile).
__global__ __launch_bounds__(256, 2)
void gemm_screen32(const unsigned short* __restrict__ zh,
                   const unsigned short* __restrict__ ch,
                   unsigned* __restrict__ cnt, int* __restrict__ cand,
                   float* __restrict__ candsc) {
    __shared__ char smem[65536];          // 2 x (64 codes x 512B), src-swizzled
    __shared__ unsigned rowmax[64];       // fkey of block-local running row max
    __shared__ unsigned cnt_l[64];        // block-local candidate counts
    __shared__ int cand_l[64][LCAP];      // block-local candidate codes
    __shared__ float score_l[64][LCAP];   // block-local candidate screen scores
    const int tid = threadIdx.x;
    const int l = tid & 63;
    const int wv = tid >> 6;        // 0..3
    const int rg = wv >> 1;         // row-group (0..1)
    const int cq = wv & 1;          // code-half (0..1)
    const int l5 = l >> 5, l31 = l & 31;
    const int n0 = blockIdx.x * 64;
    const int k0 = blockIdx.y * 4096;
    const int toff = (blockIdx.x * 37 + blockIdx.y * 29) & 63;  // decorrelate

    if (tid < 64) { rowmax[tid] = fkey(-3.0e38f); cnt_l[tid] = 0u; }

    // A fragments: 32 z-rows x all 256 d in registers.
    // 32x32x16 A-frag: lane holds A[row=l&31][k = 8*(l>>5) + j]  (HW-verified)
    bf16x8 a[16];
    {
        const unsigned short* zrow = zh + (size_t)(n0 + rg * 32 + l31) * 256;
#pragma unroll
        for (int k = 0; k < 16; ++k)
            a[k] = *(const bf16x8*)(zrow + k * 16 + l5 * 8);
    }

    // C/D mapping: row = rg*32 + 4*l5 + (r&3) + 8*(r>>2), col = cq*32 + l31
    int rown[16];
#pragma unroll
    for (int r = 0; r < 16; ++r)
        rown[r] = rg * 32 + 4 * l5 + (r & 3) + 8 * (r >> 2);

    const int lrbase = (cq * 32 + l31) * 512;

    // staging: 64 codes x 512B per tile; dest linear, XOR granule swizzle on
    // the SOURCE address (gload_lds dest is wave-uniform base + lane*16).
#define ISSUE(tphys, bufi)                                                   \
    {                                                                        \
        const unsigned short* src = ch + (size_t)(k0 + (tphys) * 64) * 256;  \
        _Pragma("unroll")                                                    \
        for (int j = 0; j < 8; ++j) {                                        \
            int cl = (wv * 8 + j) * 2 + l5;                                  \
            gload_lds16(src + cl * 256 + ((l31 ^ (cl & 31)) * 8),            \
                        smem + (bufi) * 32768 + (wv * 8 + j) * 1024);        \
        }                                                                    \
    }

    ISSUE(toff & 63, 0);   // prologue: tile 0 -> buf 0

    for (int t = 0; t < 64; ++t) {
        // one barrier per tile: drains tile-t loads (issued last iter, had a
        // full compute to land); all waves done reading the other buffer;
        // rowmax updates from tile t-1 visible.
        __syncthreads();
        float taup[16];
#pragma unroll
        for (int r = 0; r < 16; ++r)
            taup[r] = funkey(rowmax[rown[r]]) - MRG_C;
        if (t < 63) ISSUE((t + 1 + toff) & 63, (t + 1) & 1);
        const char* cur = smem + (t & 1) * 32768;
        // compute: 16 chained MFMAs
        f32x16 acc;
#pragma unroll
        for (int r = 0; r < 16; ++r) acc[r] = 0.f;
#pragma unroll
        for (int k = 0; k < 16; ++k) {
            bf16x8 b = *(const bf16x8*)(cur + lrbase + (((2 * k + l5) ^ l31) << 4));
            acc = __builtin_amdgcn_mfma_f32_32x32x16_bf16(a[k], b, acc, 0, 0, 0);
        }
        // slice max -> LDS rowmax; append (code, screen score) when >= tau
        const int code = k0 + ((t + toff) & 63) * 64 + cq * 32 + l31;
#pragma unroll
        for (int r = 0; r < 16; ++r) {
            float m = acc[r];
#pragma unroll
            for (int msk = 1; msk <= 16; msk <<= 1)
                m = fmaxf(m, __shfl_xor(m, msk));
            if (l31 == 0) atomicMax(&rowmax[rown[r]], fkey(m));   // LDS atomic
            float tau = fmaxf(taup[r], m - MRG_C);
            if (acc[r] >= tau) {
                unsigned slot = atomicAdd(&cnt_l[rown[r]], 1u);   // LDS atomic
                if (slot < LCAP) {
                    cand_l[rown[r]][slot] = code;
                    score_l[rown[r]][slot] = acc[r];
                }
            }
        }
    }

    // flush block-local candidates (one global atomicAdd per row)
    __syncthreads();
    if (tid < 64) {
        unsigned c = cnt_l[tid];
        int n = n0 + tid;
        if (c > LCAP) {
            atomicAdd(&cnt[n], 1000u);        // force exact-scan fallback
        } else if (c > 0) {
            unsigned s0 = atomicAdd(&cnt[n], c);
            for (unsigned i = 0; i < c; ++i)
                if (s0 + i < CAP) {
                    cand[n * CAP + s0 + i] = cand_l[tid][i];
                    candsc[n * CAP + s0 + i] = score_l[tid][i];
                }
            // if s0+c > CAP, final cnt > CAP -> select full-scans (safe)
        }
    }
#undef ISSUE
}

// ---------------- fused select (score-filtered rescore) + z_q + loss --------
__global__ __launch_bounds__(256)
void select_finalize(const float* __restrict__ z, const float* __restrict__ cb,
                     const float* __restrict__ zn, const unsigned* __restrict__ cnt,
                     const int* __restrict__ cand, const float* __restrict__ candsc,
                     float* __restrict__ out) {
    __shared__ float zs[64][257];
    __shared__ int codes_s[64];
    __shared__ float wsum[4];
    const int tid = threadIdx.x;
    const int nbase = blockIdx.x * 64;
    const int b = nbase >> 10, hw0 = nbase & 1023;
    const int lane = tid & 63;
    const int w = tid >> 6;

#pragma unroll 8
    for (int it = 0; it < 64; ++it) {
        int d = it * 4 + w;
        zs[lane][d] = z[(size_t)b * 262144 + (size_t)d * 1024 + hw0 + lane];
    }
    __syncthreads();

#pragma unroll 1
    for (int rr = 0; rr < 16; ++rr) {
        const int ridx = w * 16 + rr;
        const int n = nbase + ridx;
        const unsigned c = cnt[n];
        const float zz = zn[n];
        float bs; int bi;
        if (c > 0 && c <= CAP) {
            // pass 1: global screen max from stored scores (block maxima are
            // always in the lists -> max over candidates == global screen max)
            float smax = -3.0e38f;
            for (int idx = lane; idx < (int)c; idx += 64)
                smax = fmaxf(smax, candsc[n * CAP + idx]);
#pragma unroll
            for (int m = 1; m <= 32; m <<= 1)
                smax = fmaxf(smax, __shfl_xor(smax, m));
            const float tauf = smax - MRG_C;
            // pass 2: exact rescore ONLY candidates within margin (~1-3)
            float ss = 3.0e38f; int myk = 0x7fffffff;
            for (int idx = lane; idx < (int)c; idx += 64) {
                if (candsc[n * CAP + idx] >= tauf) {
                    int k2 = cand[n * CAP + idx];
                    const float* cr = cb + (size_t)k2 * 256;
                    float dot = 0.f;
#pragma unroll 8
                    for (int d4 = 0; d4 < 64; ++d4) {   // exact sequential chain
                        float4 cv = ((const float4*)cr)[d4];
                        dot = fmaf(zs[ridx][d4 * 4 + 0], cv.x, dot);
                        dot = fmaf(zs[ridx][d4 * 4 + 1], cv.y, dot);
                        dot = fmaf(zs[ridx][d4 * 4 + 2], cv.z, dot);
                        dot = fmaf(zs[ridx][d4 * 4 + 3], cv.w, dot);
                    }
                    float sc = zz - 2.0f * dot;   // reference score rounding
                    if (sc < ss || (sc == ss && k2 < myk)) { ss = sc; myk = k2; }
                }
            }
            bs = ss; bi = myk;
        } else {
            // overflow/empty fallback: exact full scan
            bs = 3.0e38f; bi = 0x7fffffff;
            for (int base = 0; base < 8192; base += 64) {
                const float* cr = cb + (size_t)(base + lane) * 256;
                float dot = 0.f;
#pragma unroll 8
                for (int d4 = 0; d4 < 64; ++d4) {
                    float4 cv = ((const float4*)cr)[d4];
                    dot = fmaf(zs[ridx][d4 * 4 + 0], cv.x, dot);
                    dot = fmaf(zs[ridx][d4 * 4 + 1], cv.y, dot);
                    dot = fmaf(zs[ridx][d4 * 4 + 2], cv.z, dot);
                    dot = fmaf(zs[ridx][d4 * 4 + 3], cv.w, dot);
                }
                float sc = zz - 2.0f * dot;
                int k = base + lane;
                if (sc < bs || (sc == bs && k < bi)) { bs = sc; bi = k; }
            }
        }
#pragma unroll
        for (int m = 1; m <= 32; m <<= 1) {
            float ps = __shfl_xor(bs, m);
            int pi = __shfl_xor(bi, m);
            if (ps < bs || (ps == bs && pi < bi)) { bs = ps; bi = pi; }
        }
        if (lane == 0) { codes_s[ridx] = bi; out[4194305 + n] = (float)bi; }
    }
    __syncthreads();

    const int code = codes_s[lane];
    const float* crow = cb + (size_t)code * 256;
    float part = 0.f;
#pragma unroll 8
    for (int j = 0; j < 64; ++j) {
        int d = w * 64 + j;
        float cv = crow[d];
        float ze = zs[lane][d];
        out[(size_t)b * 262144 + (size_t)d * 1024 + hw0 + lane] = cv;
        float diff = ze - cv;
        part += diff * diff;
    }
#pragma unroll
    for (int off = 32; off > 0; off >>= 1) part += __shfl_down(part, off);
    if (lane == 0) wsum[w] = part;
    __syncthreads();
    if (tid == 0) {
        float t = (wsum[0] + wsum[1] + wsum[2] + wsum[3]) * (1.25f / 4194304.f);
        atomicAdd(out + 4194304, t);
    }
}

// ================= fallback path (round-2 kernels, ws-small case) =================
#define NT 128
#define KT 128
#define DC 64
#define KS 4
#define KRANGE (8192 / KS)
#define PSCORE_OFF 32768
#define PIDX_OFF (32768 + KS * 16384)

__global__ __launch_bounds__(256)
void znorm_kernel(const float* __restrict__ z, float* __restrict__ zn) {
    int n = blockIdx.x * 256 + threadIdx.x;
    int b = n >> 10, hw = n & 1023;
    const float* zp = z + (size_t)b * 262144 + hw;
    float s = 0.f;
    for (int d = 0; d < 256; ++d) {
        float v = zp[(size_t)d << 10];
        s += v * v;
    }
    zn[n] = s;
}

__global__ __launch_bounds__(256, 2)
void dist_argmin_kernel(const float* __restrict__ z, const float* __restrict__ cb,
                        const float* __restrict__ zn,
                        float* __restrict__ pscore, int* __restrict__ pidx) {
    __shared__ float zs[DC][NT];
    __shared__ float cs[DC][KT];
    const int tid = threadIdx.x;
    const int tn = tid & 15;
    const int tk = tid >> 4;
    const int n0 = blockIdx.x * NT;
    const int b = n0 >> 10;
    const int hw0 = n0 & 1023;
    const float* zb = z + (size_t)b * 262144 + hw0;
    const int k0base = blockIdx.y * KRANGE;
    float zzr[8];
#pragma unroll
    for (int i = 0; i < 8; ++i) {
        int row = (i < 4) ? (tn * 4 + i) : (64 + tn * 4 + (i - 4));
        zzr[i] = zn[n0 + row];
    }
    float best[8]; int bidx[8];
#pragma unroll
    for (int i = 0; i < 8; ++i) { best[i] = 3.0e38f; bidx[i] = 0; }
    for (int kt = 0; kt < KRANGE / KT; ++kt) {
        const int k0 = k0base + kt * KT;
        float acc[8][8];
#pragma unroll
        for (int i = 0; i < 8; ++i)
#pragma unroll
            for (int j = 0; j < 8; ++j) acc[i][j] = 0.f;
        for (int dc = 0; dc < 256; dc += DC) {
            __syncthreads();
#pragma unroll
            for (int it = 0; it < 8; ++it) {
                int idx = it * 256 + tid;
                int d = idx >> 5, nv = idx & 31;
                float4 v = *(const float4*)(zb + (size_t)(dc + d) * 1024 + nv * 4);
                *(float4*)&zs[d][nv * 4] = v;
            }
#pragma unroll
            for (int it = 0; it < 8; ++it) {
                int idx = it * 256 + tid;
                int k = idx >> 4, dv = idx & 15;
                float4 v = *(const float4*)(cb + (size_t)(k0 + k) * 256 + dc + dv * 4);
                int colv = k ^ ((dv & 7) << 2);
                cs[dv * 4 + 0][colv] = v.x;
                cs[dv * 4 + 1][colv] = v.y;
                cs[dv * 4 + 2][colv] = v.z;
                cs[dv * 4 + 3][colv] = v.w;
            }
            __syncthreads();
#pragma unroll 2
            for (int d = 0; d < DC; ++d) {
                int swz = ((d >> 2) & 7) << 2;
                float4 a0 = *(const float4*)&zs[d][tn * 4];
                float4 a1 = *(const float4*)&zs[d][64 + tn * 4];
                float4 b0 = *(const float4*)&cs[d][(tk * 4) ^ swz];
                float4 b1 = *(const float4*)&cs[d][(64 + tk * 4) ^ swz];
                float av[8] = {a0.x, a0.y, a0.z, a0.w, a1.x, a1.y, a1.z, a1.w};
                float bv[8] = {b0.x, b0.y, b0.z, b0.w, b1.x, b1.y, b1.z, b1.w};
#pragma unroll
                for (int i = 0; i < 8; ++i)
#pragma unroll
                    for (int j = 0; j < 8; ++j)
                        acc[i][j] = fmaf(av[i], bv[j], acc[i][j]);
            }
        }
#pragma unroll
        for (int j = 0; j < 8; ++j) {
            int kloc = (j < 4) ? (tk * 4 + j) : (64 + tk * 4 + (j - 4));
            int kk = k0 + kloc;
#pragma unroll
            for (int i = 0; i < 8; ++i) {
                float s = zzr[i] - 2.0f * acc[i][j];
                if (s < best[i]) { best[i] = s; bidx[i] = kk; }
            }
        }
    }
    __syncthreads();
    float* sredf = &zs[0][0];
    int* sredi = (int*)&cs[0][0];
#pragma unroll
    for (int i = 0; i < 8; ++i) {
        int row = (i < 4) ? (tn * 4 + i) : (64 + tn * 4 + (i - 4));
        sredf[row * 16 + tk] = best[i];
        sredi[row * 16 + tk] = bidx[i];
    }
    __syncthreads();
    if (tid < NT) {
        float bs = sredf[tid * 16];
        int bi = sredi[tid * 16];
#pragma unroll
        for (int t = 1; t < 16; ++t) {
            float s = sredf[tid * 16 + t];
            int ix = sredi[tid * 16 + t];
            if (s < bs || (s == bs && ix < bi)) { bs = s; bi = ix; }
        }
        pscore[blockIdx.y * 16384 + n0 + tid] = bs;
        pidx[blockIdx.y * 16384 + n0 + tid] = bi;
    }
}

__global__ __launch_bounds__(256)
void finalize_kernel(const float* __restrict__ z, const float* __restrict__ cb,
                     const float* __restrict__ pscore, const int* __restrict__ pidx,
                     float* __restrict__ out) {
    __shared__ int codes_s[64];
    __shared__ float wsum[4];
    const int nbase = blockIdx.x * 64;
    const int tid = threadIdx.x;
    if (tid < 64) {
        int n = nbase + tid;
        float bs = pscore[n];
        int bi = pidx[n];
#pragma unroll
        for (int p = 1; p < KS; ++p) {
            float s = pscore[p * 16384 + n];
            int ix = pidx[p * 16384 + n];
            if (s < bs || (s == bs && ix < bi)) { bs = s; bi = ix; }
        }
        codes_s[tid] = bi;
        out[4194305 + n] = (float)bi;
    }
    __syncthreads();
    const int lane = tid & 63;
    const int w = tid >> 6;
    const int n = nbase + lane;
    const int b = n >> 10, hw = n & 1023;
    const int code = codes_s[lane];
    const float* crow = cb + (size_t)code * 256;
    const float* zrow = z + (size_t)b * 262144 + hw;
    float* orow = out + (size_t)b * 262144 + hw;
    float part = 0.f;
    for (int j = 0; j < 64; ++j) {
        int d = w * 64 + j;
        float cv = crow[d];
        float ze = zrow[(size_t)d * 1024];
        orow[(size_t)d * 1024] = cv;
        float diff = ze - cv;
        part += diff * diff;
    }
#pragma unroll
    for (int off = 32; off > 0; off >>= 1) part += __shfl_down(part, off);
    if (lane == 0) wsum[w] = part;
    __syncthreads();
    if (tid == 0) {
        float t = (wsum[0] + wsum[1] + wsum[2] + wsum[3]) * (1.25f / 4194304.f);
        atomicAdd(out + 4194304, t);
    }
}

// ================= launcher =================
extern "C" void kernel_launch(void* const* d_in, const int* in_sizes, int n_in,
                              void* d_out, int out_size, void* d_ws, size_t ws_size,
                              hipStream_t stream) {
    const float* z = (const float*)d_in[0];
    const float* cb = (const float*)d_in[1];
    float* out = (float*)d_out;
    char* wsb = (char*)d_ws;

    if (ws_size >= WS_NEED) {
        float* zn = (float*)(wsb + ZN_B);
        unsigned* cnt = (unsigned*)(wsb + CNT_B);
        int* cand = (int*)(wsb + CAND_B);
        float* candsc = (float*)(wsb + CANDSC_B);
        unsigned short* zh = (unsigned short*)(wsb + ZH_B);
        unsigned short* ch = (unsigned short*)(wsb + CH_B);

        hipMemsetAsync(wsb + CNT_B, 0, 65536, stream);
        hipMemsetAsync(out + 4194304, 0, sizeof(float), stream);

        prep_z_kernel<<<256, 256, 0, stream>>>(z, zn, zh);
        split_c_kernel<<<2048, 256, 0, stream>>>(cb, ch);
        gemm_screen32<<<dim3(256, 2), 256, 0, stream>>>(zh, ch, cnt, cand, candsc);
        select_finalize<<<256, 256, 0, stream>>>(z, cb, zn, cnt, cand, candsc, out);
    } else {
        float* zn = (float*)wsb;
        float* pscore = (float*)wsb + PSCORE_OFF;
        int* pidx = (int*)((float*)wsb + PIDX_OFF);
        znorm_kernel<<<64, 256, 0, stream>>>(z, zn);
        dim3 grid(16384 / NT, KS);
        dist_argmin_kernel<<<grid, 256, 0, stream>>>(z, cb, zn, pscore, pidx);
        hipMemsetAsync(out + 4194304, 0, sizeof(float), stream);
        finalize_kernel<<<16384 / 64, 256, 0, stream>>>(z, cb, pscore, pidx, out);
    }
}

// Round 12
// 966.925 us; speedup vs baseline: 1.5367x; 1.5367x over previous
//
#include <hip/hip_runtime.h>

// VQ codebook: z_e (16,256,32,32) f32, codebook (8192,256) f32.
// out f32: z_q_st[4194304] | loss[1] | codes[16384].
// n = b*1024+hw; z_flat[n][d] = z_e[b*262144 + d*1024 + hw]
// Reference: dist = fl32(zz - 2*dot), dot = sequential f32 FMA chain d=0..255,
// argmin ties -> lowest index (validated bitwise in round 2).
//
// Round-12 screen: BARRIER-FREE. B-fragments load directly global->VGPR (the
// LDS staging round-trip bought nothing: each line consumed once per wave).
// Threshold: cached rowmax + predicated LDS atomicMax (fires only on records)
// + broadcast ds_read; no shuffles in the loop. Safety: rowmax is monotone
// and <= block max, so every code with score >= blockmax-MRG >= gmax-MRG is
// appended; select rescores exactly those within MRG of the global screen max.

#define CAP 112       // global per-row candidate cap (= 4 blocks * LCAP)
#define LCAP 28       // per-block LDS candidate cap per row
#define MRG_C 1.96e-4f // dot-domain: 1.5*max ulp(zz) + 2*bf16 screen err bound

typedef short bf16x8 __attribute__((ext_vector_type(8)));
typedef float f32x16 __attribute__((ext_vector_type(16)));

__device__ __forceinline__ unsigned short f2bf(float f) {
    unsigned u = __float_as_uint(f);
    return (unsigned short)((u + 0x7fffu + ((u >> 16) & 1u)) >> 16);
}
// monotone float<->uint key (total order matches float order)
__device__ __forceinline__ unsigned fkey(float f) {
    unsigned u = __float_as_uint(f);
    return (u & 0x80000000u) ? ~u : (u | 0x80000000u);
}
__device__ __forceinline__ float funkey(unsigned k) {
    unsigned u = (k & 0x80000000u) ? (k ^ 0x80000000u) : ~k;
    return __uint_as_float(u);
}

// ---- ws byte layout (big path); WS_NEED <= 29,360,128 (r3-proven size) ----
#define ZN_B      0u          // f32[16384]
#define CNT_B     65536u      // u32[16384]
#define CAND_B    131072u     // i32[16384*CAP]  = 7.34 MB
#define CANDSC_B  7471104u    // f32[16384*CAP]  = 7.34 MB
#define ZH_B      14811136u   // bf16[16384][256] = 8 MB
#define CH_B      23199744u   // bf16[8192][256] = 4 MB
#define WS_NEED   27394048u

// ---------------- prep: z norms + bf16 transpose (fused) ----------------
__global__ __launch_bounds__(256)
void prep_z_kernel(const float* __restrict__ z, float* __restrict__ zn,
                   unsigned short* __restrict__ zh) {
    __shared__ float zs[64][257];
    const int tid = threadIdx.x;
    const int nbase = blockIdx.x * 64;
    const int b = nbase >> 10, hw0 = nbase & 1023;
    const int lane = tid & 63;
    const int w = tid >> 6;
#pragma unroll 8
    for (int it = 0; it < 64; ++it) {
        int d = it * 4 + w;
        zs[lane][d] = z[(size_t)b * 262144 + (size_t)d * 1024 + hw0 + lane];
    }
    __syncthreads();
    if (tid < 64) {
        float s = 0.f;
        for (int d = 0; d < 256; ++d) {
            float v = zs[tid][d];
            s += v * v;
        }
        zn[nbase + tid] = s;
    }
#pragma unroll 4
    for (int it = 0; it < 16; ++it) {
        int idx = it * 256 + tid;
        int row = idx >> 6;
        int d4 = idx & 63;
        ushort4 hv;
        hv.x = f2bf(zs[row][d4 * 4 + 0]);
        hv.y = f2bf(zs[row][d4 * 4 + 1]);
        hv.z = f2bf(zs[row][d4 * 4 + 2]);
        hv.w = f2bf(zs[row][d4 * 4 + 3]);
        ((ushort4*)(zh + (size_t)(nbase + row) * 256))[d4] = hv;
    }
}

// ---------------- prep: codebook -> bf16 ----------------
__global__ __launch_bounds__(256)
void split_c_kernel(const float* __restrict__ cb, unsigned short* __restrict__ ch) {
    int gid = blockIdx.x * 256 + threadIdx.x;     // float4 index; 524288 total
    float4 v = ((const float4*)cb)[gid];
    ushort4 hv;
    hv.x = f2bf(v.x); hv.y = f2bf(v.y); hv.z = f2bf(v.z); hv.w = f2bf(v.w);
    ((ushort4*)ch)[gid] = hv;
}

// ---------------- screening GEMM (32x32x16, barrier-free direct-load) ------
// grid (256 row-tiles, 4 k-splits) x 256 thr (4 waves = 2 rg x 2 cq).
// Block: 64 rows x 2048 codes in 32 tiles of 64 codes (32/wave-slice).
__global__ __launch_bounds__(256, 2)
void gemm_screen32(const unsigned short* __restrict__ zh,
                   const unsigned short* __restrict__ ch,
                   unsigned* __restrict__ cnt, int* __restrict__ cand,
                   float* __restrict__ candsc) {
    __shared__ unsigned rowmax[64];       // fkey of block-local running row max
    __shared__ unsigned cnt_l[64];        // block-local candidate counts
    __shared__ int cand_l[64][LCAP];      // block-local candidate codes
    __shared__ float score_l[64][LCAP];   // block-local candidate screen scores
    const int tid = threadIdx.x;
    const int l = tid & 63;
    const int wv = tid >> 6;        // 0..3
    const int rg = wv >> 1;         // row-group (0..1)
    const int cq = wv & 1;          // code-half (0..1)
    const int l5 = l >> 5, l31 = l & 31;
    const int n0 = blockIdx.x * 64;
    const int k0 = blockIdx.y * 2048;
    const int toff = (blockIdx.x * 7 + blockIdx.y * 13) & 31;  // decorrelate

    if (tid < 64) { rowmax[tid] = fkey(-3.0e38f); cnt_l[tid] = 0u; }
    __syncthreads();   // init visible (only barrier in the kernel)

    // A fragments: 32 z-rows x all 256 d in registers (64 VGPR).
    // 32x32x16 A-frag: lane holds A[row=l&31][k = 8*(l>>5) + j]  (HW-verified)
    bf16x8 a[16];
    {
        const unsigned short* zrow = zh + (size_t)(n0 + rg * 32 + l31) * 256;
#pragma unroll
        for (int k = 0; k < 16; ++k)
            a[k] = *(const bf16x8*)(zrow + k * 16 + l5 * 8);
    }

    // C/D mapping: row = rg*32 + 4*l5 + (r&3) + 8*(r>>2), col = cq*32 + l31
    int rown[16];
    float rmc[16];   // cached block rowmax (stale-low-safe, monotone)
#pragma unroll
    for (int r = 0; r < 16; ++r) {
        rown[r] = rg * 32 + 4 * l5 + (r & 3) + 8 * (r >> 2);
        rmc[r] = -3.0e38f;
    }

#pragma unroll 2
    for (int t = 0; t < 32; ++t) {
        const int tphys = (t + toff) & 31;
        const int kb = k0 + tphys * 64 + cq * 32;   // this wave's 32 codes
        // B fragments straight from L2: lane reads ch[(kb+l31)*256 + k*16+l5*8]
        const unsigned short* crow = ch + (size_t)(kb + l31) * 256 + l5 * 8;
        bf16x8 bfr[16];
#pragma unroll
        for (int k = 0; k < 16; ++k)
            bfr[k] = *(const bf16x8*)(crow + k * 16);
        f32x16 acc;
#pragma unroll
        for (int r = 0; r < 16; ++r) acc[r] = 0.f;
#pragma unroll
        for (int k = 0; k < 16; ++k)
            acc = __builtin_amdgcn_mfma_f32_32x32x16_bf16(a[k], bfr[k], acc, 0, 0, 0);
        // record update (predicated atomic: exec-empty on non-record tiles),
        // then broadcast re-read -> fresh tau including own wave's records.
        const int code = kb + l31;
#pragma unroll
        for (int r = 0; r < 16; ++r) {
            if (acc[r] > rmc[r])
                atomicMax(&rowmax[rown[r]], fkey(acc[r]));        // LDS atomic
            rmc[r] = funkey(rowmax[rown[r]]);                     // broadcast
            if (acc[r] >= rmc[r] - MRG_C) {
                unsigned slot = atomicAdd(&cnt_l[rown[r]], 1u);   // LDS atomic
                if (slot < LCAP) {
                    cand_l[rown[r]][slot] = code;
                    score_l[rown[r]][slot] = acc[r];
                }
            }
        }
    }

    // flush block-local candidates (one global atomicAdd per row)
    __syncthreads();
    if (tid < 64) {
        unsigned c = cnt_l[tid];
        int n = n0 + tid;
        if (c > LCAP) {
            atomicAdd(&cnt[n], 1000u);        // force exact-scan fallback
        } else if (c > 0) {
            unsigned s0 = atomicAdd(&cnt[n], c);
            for (unsigned i = 0; i < c; ++i)
                if (s0 + i < CAP) {
                    cand[n * CAP + s0 + i] = cand_l[tid][i];
                    candsc[n * CAP + s0 + i] = score_l[tid][i];
                }
        }
    }
}

// ---------------- fused select (score-filtered rescore) + z_q + loss --------
__global__ __launch_bounds__(256)
void select_finalize(const float* __restrict__ z, const float* __restrict__ cb,
                     const float* __restrict__ zn, const unsigned* __restrict__ cnt,
                     const int* __restrict__ cand, const float* __restrict__ candsc,
                     float* __restrict__ out) {
    __shared__ float zs[64][257];
    __shared__ int codes_s[64];
    __shared__ float wsum[4];
    const int tid = threadIdx.x;
    const int nbase = blockIdx.x * 64;
    const int b = nbase >> 10, hw0 = nbase & 1023;
    const int lane = tid & 63;
    const int w = tid >> 6;

#pragma unroll 8
    for (int it = 0; it < 64; ++it) {
        int d = it * 4 + w;
        zs[lane][d] = z[(size_t)b * 262144 + (size_t)d * 1024 + hw0 + lane];
    }
    __syncthreads();

#pragma unroll 1
    for (int rr = 0; rr < 16; ++rr) {
        const int ridx = w * 16 + rr;
        const int n = nbase + ridx;
        const unsigned c = cnt[n];
        const float zz = zn[n];
        float bs; int bi;
        if (c > 0 && c <= CAP) {
            // pass 1: global screen max from stored scores (block maxima are
            // always stored -> max over candidates == global screen max)
            float smax = -3.0e38f;
            for (int idx = lane; idx < (int)c; idx += 64)
                smax = fmaxf(smax, candsc[n * CAP + idx]);
#pragma unroll
            for (int m = 1; m <= 32; m <<= 1)
                smax = fmaxf(smax, __shfl_xor(smax, m));
            const float tauf = smax - MRG_C;
            // pass 2: exact rescore ONLY candidates within margin (~1-3/row)
            float ss = 3.0e38f; int myk = 0x7fffffff;
            for (int idx = lane; idx < (int)c; idx += 64) {
                if (candsc[n * CAP + idx] >= tauf) {
                    int k2 = cand[n * CAP + idx];
                    const float* cr = cb + (size_t)k2 * 256;
                    float dot = 0.f;
#pragma unroll 8
                    for (int d4 = 0; d4 < 64; ++d4) {   // exact sequential chain
                        float4 cv = ((const float4*)cr)[d4];
                        dot = fmaf(zs[ridx][d4 * 4 + 0], cv.x, dot);
                        dot = fmaf(zs[ridx][d4 * 4 + 1], cv.y, dot);
                        dot = fmaf(zs[ridx][d4 * 4 + 2], cv.z, dot);
                        dot = fmaf(zs[ridx][d4 * 4 + 3], cv.w, dot);
                    }
                    float sc = zz - 2.0f * dot;   // reference score rounding
                    if (sc < ss || (sc == ss && k2 < myk)) { ss = sc; myk = k2; }
                }
            }
            bs = ss; bi = myk;
        } else {
            // overflow/empty fallback: exact full scan (P ~ 1e-9)
            bs = 3.0e38f; bi = 0x7fffffff;
            for (int base = 0; base < 8192; base += 64) {
                const float* cr = cb + (size_t)(base + lane) * 256;
                float dot = 0.f;
#pragma unroll 8
                for (int d4 = 0; d4 < 64; ++d4) {
                    float4 cv = ((const float4*)cr)[d4];
                    dot = fmaf(zs[ridx][d4 * 4 + 0], cv.x, dot);
                    dot = fmaf(zs[ridx][d4 * 4 + 1], cv.y, dot);
                    dot = fmaf(zs[ridx][d4 * 4 + 2], cv.z, dot);
                    dot = fmaf(zs[ridx][d4 * 4 + 3], cv.w, dot);
                }
                float sc = zz - 2.0f * dot;
                int k = base + lane;
                if (sc < bs || (sc == bs && k < bi)) { bs = sc; bi = k; }
            }
        }
#pragma unroll
        for (int m = 1; m <= 32; m <<= 1) {
            float ps = __shfl_xor(bs, m);
            int pi = __shfl_xor(bi, m);
            if (ps < bs || (ps == bs && pi < bi)) { bs = ps; bi = pi; }
        }
        if (lane == 0) { codes_s[ridx] = bi; out[4194305 + n] = (float)bi; }
    }
    __syncthreads();

    const int code = codes_s[lane];
    const float* crow = cb + (size_t)code * 256;
    float part = 0.f;
#pragma unroll 8
    for (int j = 0; j < 64; ++j) {
        int d = w * 64 + j;
        float cv = crow[d];
        float ze = zs[lane][d];
        out[(size_t)b * 262144 + (size_t)d * 1024 + hw0 + lane] = cv;
        float diff = ze - cv;
        part += diff * diff;
    }
#pragma unroll
    for (int off = 32; off > 0; off >>= 1) part += __shfl_down(part, off);
    if (lane == 0) wsum[w] = part;
    __syncthreads();
    if (tid == 0) {
        float t = (wsum[0] + wsum[1] + wsum[2] + wsum[3]) * (1.25f / 4194304.f);
        atomicAdd(out + 4194304, t);
    }
}

// ================= fallback path (round-2 kernels, ws-small case) =================
#define NT 128
#define KT 128
#define DC 64
#define KS 4
#define KRANGE (8192 / KS)
#define PSCORE_OFF 32768
#define PIDX_OFF (32768 + KS * 16384)

__global__ __launch_bounds__(256)
void znorm_kernel(const float* __restrict__ z, float* __restrict__ zn) {
    int n = blockIdx.x * 256 + threadIdx.x;
    int b = n >> 10, hw = n & 1023;
    const float* zp = z + (size_t)b * 262144 + hw;
    float s = 0.f;
    for (int d = 0; d < 256; ++d) {
        float v = zp[(size_t)d << 10];
        s += v * v;
    }
    zn[n] = s;
}

__global__ __launch_bounds__(256, 2)
void dist_argmin_kernel(const float* __restrict__ z, const float* __restrict__ cb,
                        const float* __restrict__ zn,
                        float* __restrict__ pscore, int* __restrict__ pidx) {
    __shared__ float zs[DC][NT];
    __shared__ float cs[DC][KT];
    const int tid = threadIdx.x;
    const int tn = tid & 15;
    const int tk = tid >> 4;
    const int n0 = blockIdx.x * NT;
    const int b = n0 >> 10;
    const int hw0 = n0 & 1023;
    const float* zb = z + (size_t)b * 262144 + hw0;
    const int k0base = blockIdx.y * KRANGE;
    float zzr[8];
#pragma unroll
    for (int i = 0; i < 8; ++i) {
        int row = (i < 4) ? (tn * 4 + i) : (64 + tn * 4 + (i - 4));
        zzr[i] = zn[n0 + row];
    }
    float best[8]; int bidx[8];
#pragma unroll
    for (int i = 0; i < 8; ++i) { best[i] = 3.0e38f; bidx[i] = 0; }
    for (int kt = 0; kt < KRANGE / KT; ++kt) {
        const int k0 = k0base + kt * KT;
        float acc[8][8];
#pragma unroll
        for (int i = 0; i < 8; ++i)
#pragma unroll
            for (int j = 0; j < 8; ++j) acc[i][j] = 0.f;
        for (int dc = 0; dc < 256; dc += DC) {
            __syncthreads();
#pragma unroll
            for (int it = 0; it < 8; ++it) {
                int idx = it * 256 + tid;
                int d = idx >> 5, nv = idx & 31;
                float4 v = *(const float4*)(zb + (size_t)(dc + d) * 1024 + nv * 4);
                *(float4*)&zs[d][nv * 4] = v;
            }
#pragma unroll
            for (int it = 0; it < 8; ++it) {
                int idx = it * 256 + tid;
                int k = idx >> 4, dv = idx & 15;
                float4 v = *(const float4*)(cb + (size_t)(k0 + k) * 256 + dc + dv * 4);
                int colv = k ^ ((dv & 7) << 2);
                cs[dv * 4 + 0][colv] = v.x;
                cs[dv * 4 + 1][colv] = v.y;
                cs[dv * 4 + 2][colv] = v.z;
                cs[dv * 4 + 3][colv] = v.w;
            }
            __syncthreads();
#pragma unroll 2
            for (int d = 0; d < DC; ++d) {
                int swz = ((d >> 2) & 7) << 2;
                float4 a0 = *(const float4*)&zs[d][tn * 4];
                float4 a1 = *(const float4*)&zs[d][64 + tn * 4];
                float4 b0 = *(const float4*)&cs[d][(tk * 4) ^ swz];
                float4 b1 = *(const float4*)&cs[d][(64 + tk * 4) ^ swz];
                float av[8] = {a0.x, a0.y, a0.z, a0.w, a1.x, a1.y, a1.z, a1.w};
                float bv[8] = {b0.x, b0.y, b0.z, b0.w, b1.x, b1.y, b1.z, b1.w};
#pragma unroll
                for (int i = 0; i < 8; ++i)
#pragma unroll
                    for (int j = 0; j < 8; ++j)
                        acc[i][j] = fmaf(av[i], bv[j], acc[i][j]);
            }
        }
#pragma unroll
        for (int j = 0; j < 8; ++j) {
            int kloc = (j < 4) ? (tk * 4 + j) : (64 + tk * 4 + (j - 4));
            int kk = k0 + kloc;
#pragma unroll
            for (int i = 0; i < 8; ++i) {
                float s = zzr[i] - 2.0f * acc[i][j];
                if (s < best[i]) { best[i] = s; bidx[i] = kk; }
            }
        }
    }
    __syncthreads();
    float* sredf = &zs[0][0];
    int* sredi = (int*)&cs[0][0];
#pragma unroll
    for (int i = 0; i < 8; ++i) {
        int row = (i < 4) ? (tn * 4 + i) : (64 + tn * 4 + (i - 4));
        sredf[row * 16 + tk] = best[i];
        sredi[row * 16 + tk] = bidx[i];
    }
    __syncthreads();
    if (tid < NT) {
        float bs = sredf[tid * 16];
        int bi = sredi[tid * 16];
#pragma unroll
        for (int t = 1; t < 16; ++t) {
            float s = sredf[tid * 16 + t];
            int ix = sredi[tid * 16 + t];
            if (s < bs || (s == bs && ix < bi)) { bs = s; bi = ix; }
        }
        pscore[blockIdx.y * 16384 + n0 + tid] = bs;
        pidx[blockIdx.y * 16384 + n0 + tid] = bi;
    }
}

__global__ __launch_bounds__(256)
void finalize_kernel(const float* __restrict__ z, const float* __restrict__ cb,
                     const float* __restrict__ pscore, const int* __restrict__ pidx,
                     float* __restrict__ out) {
    __shared__ int codes_s[64];
    __shared__ float wsum[4];
    const int nbase = blockIdx.x * 64;
    const int tid = threadIdx.x;
    if (tid < 64) {
        int n = nbase + tid;
        float bs = pscore[n];
        int bi = pidx[n];
#pragma unroll
        for (int p = 1; p < KS; ++p) {
            float s = pscore[p * 16384 + n];
            int ix = pidx[p * 16384 + n];
            if (s < bs || (s == bs && ix < bi)) { bs = s; bi = ix; }
        }
        codes_s[tid] = bi;
        out[4194305 + n] = (float)bi;
    }
    __syncthreads();
    const int lane = tid & 63;
    const int w = tid >> 6;
    const int n = nbase + lane;
    const int b = n >> 10, hw = n & 1023;
    const int code = codes_s[lane];
    const float* crow = cb + (size_t)code * 256;
    const float* zrow = z + (size_t)b * 262144 + hw;
    float* orow = out + (size_t)b * 262144 + hw;
    float part = 0.f;
    for (int j = 0; j < 64; ++j) {
        int d = w * 64 + j;
        float cv = crow[d];
        float ze = zrow[(size_t)d * 1024];
        orow[(size_t)d * 1024] = cv;
        float diff = ze - cv;
        part += diff * diff;
    }
#pragma unroll
    for (int off = 32; off > 0; off >>= 1) part += __shfl_down(part, off);
    if (lane == 0) wsum[w] = part;
    __syncthreads();
    if (tid == 0) {
        float t = (wsum[0] + wsum[1] + wsum[2] + wsum[3]) * (1.25f / 4194304.f);
        atomicAdd(out + 4194304, t);
    }
}

// ================= launcher =================
extern "C" void kernel_launch(void* const* d_in, const int* in_sizes, int n_in,
                              void* d_out, int out_size, void* d_ws, size_t ws_size,
                              hipStream_t stream) {
    const float* z = (const float*)d_in[0];
    const float* cb = (const float*)d_in[1];
    float* out = (float*)d_out;
    char* wsb = (char*)d_ws;

    if (ws_size >= WS_NEED) {
        float* zn = (float*)(wsb + ZN_B);
        unsigned* cnt = (unsigned*)(wsb + CNT_B);
        int* cand = (int*)(wsb + CAND_B);
        float* candsc = (float*)(wsb + CANDSC_B);
        unsigned short* zh = (unsigned short*)(wsb + ZH_B);
        unsigned short* ch = (unsigned short*)(wsb + CH_B);

        hipMemsetAsync(wsb + CNT_B, 0, 65536, stream);
        hipMemsetAsync(out + 4194304, 0, sizeof(float), stream);

        prep_z_kernel<<<256, 256, 0, stream>>>(z, zn, zh);
        split_c_kernel<<<2048, 256, 0, stream>>>(cb, ch);
        gemm_screen32<<<dim3(256, 4), 256, 0, stream>>>(zh, ch, cnt, cand, candsc);
        select_finalize<<<256, 256, 0, stream>>>(z, cb, zn, cnt, cand, candsc, out);
    } else {
        float* zn = (float*)wsb;
        float* pscore = (float*)wsb + PSCORE_OFF;
        int* pidx = (int*)((float*)wsb + PIDX_OFF);
        znorm_kernel<<<64, 256, 0, stream>>>(z, zn);
        dim3 grid(16384 / NT, KS);
        dist_argmin_kernel<<<grid, 256, 0, stream>>>(z, cb, zn, pscore, pidx);
        hipMemsetAsync(out + 4194304, 0, sizeof(float), stream);
        finalize_kernel<<<16384 / 64, 256, 0, stream>>>(z, cb, pscore, pidx, out);
    }
}

// Round 13
// 463.738 us; speedup vs baseline: 3.2042x; 2.0851x over previous
//
#include <hip/hip_runtime.h>

// VQ codebook: z_e (16,256,32,32) f32, codebook (8192,256) f32.
// out f32: z_q_st[4194304] | loss[1] | codes[16384].
// n = b*1024+hw; z_flat[n][d] = z_e[b*262144 + d*1024 + hw]
// Reference: dist = fl32(zz - 2*dot), dot = sequential f32 FMA chain d=0..255,
// argmin ties -> lowest index (validated bitwise in round 2).
//
// Round-13: screen is BYTES-BOUND (~300us at 1GB codebook stream across r6-r12
// regardless of structure). (a) 128-row blocks with TWO register A-sets halve
// codebook traffic to 0.5GB. (b) candidates packed (score16|code) in one u32,
// LCAP=48, CAP=128 >= 2*LCAP -> global truncation impossible; select filter
// margin widened by 2*ulp16. Barrier-free loop, cached-rmc threshold (r12).

#define CAP 128        // global per-row cap (2 blocks x LCAP max = 96 < CAP)
#define LCAP 48        // per-block LDS cap per row
#define MRG_C 1.96e-4f // dot-domain: 1.5*max ulp(zz) + 2*bf16 screen err bound
#define MRG_SEL 6.9e-4f // MRG_C + 2*ulp16 (16-bit key truncation, |s|<~0.04)

typedef short bf16x8 __attribute__((ext_vector_type(8)));
typedef float f32x16 __attribute__((ext_vector_type(16)));

__device__ __forceinline__ unsigned short f2bf(float f) {
    unsigned u = __float_as_uint(f);
    return (unsigned short)((u + 0x7fffu + ((u >> 16) & 1u)) >> 16);
}
// monotone float<->uint key (total order matches float order)
__device__ __forceinline__ unsigned fkey(float f) {
    unsigned u = __float_as_uint(f);
    return (u & 0x80000000u) ? ~u : (u | 0x80000000u);
}
__device__ __forceinline__ float funkey(unsigned k) {
    unsigned u = (k & 0x80000000u) ? (k ^ 0x80000000u) : ~k;
    return __uint_as_float(u);
}

// ---- ws byte layout (big path); WS_NEED <= 27,394,048 (r12-proven size) ----
#define ZN_B      0u          // f32[16384]
#define CNT_B     65536u      // u32[16384]
#define CAND_B    131072u     // u32[16384*CAP] = 8 MB (packed score16|code)
#define ZH_B      8519680u    // bf16[16384][256] = 8 MB
#define CH_B      16908288u   // bf16[8192][256] = 4 MB
#define WS_NEED   21102592u

// ---------------- prep: z norms + bf16 transpose (fused) ----------------
__global__ __launch_bounds__(256)
void prep_z_kernel(const float* __restrict__ z, float* __restrict__ zn,
                   unsigned short* __restrict__ zh) {
    __shared__ float zs[64][257];
    const int tid = threadIdx.x;
    const int nbase = blockIdx.x * 64;
    const int b = nbase >> 10, hw0 = nbase & 1023;
    const int lane = tid & 63;
    const int w = tid >> 6;
#pragma unroll 8
    for (int it = 0; it < 64; ++it) {
        int d = it * 4 + w;
        zs[lane][d] = z[(size_t)b * 262144 + (size_t)d * 1024 + hw0 + lane];
    }
    __syncthreads();
    if (tid < 64) {
        float s = 0.f;
        for (int d = 0; d < 256; ++d) {
            float v = zs[tid][d];
            s += v * v;
        }
        zn[nbase + tid] = s;
    }
#pragma unroll 4
    for (int it = 0; it < 16; ++it) {
        int idx = it * 256 + tid;
        int row = idx >> 6;
        int d4 = idx & 63;
        ushort4 hv;
        hv.x = f2bf(zs[row][d4 * 4 + 0]);
        hv.y = f2bf(zs[row][d4 * 4 + 1]);
        hv.z = f2bf(zs[row][d4 * 4 + 2]);
        hv.w = f2bf(zs[row][d4 * 4 + 3]);
        ((ushort4*)(zh + (size_t)(nbase + row) * 256))[d4] = hv;
    }
}

// ---------------- prep: codebook -> bf16 ----------------
__global__ __launch_bounds__(256)
void split_c_kernel(const float* __restrict__ cb, unsigned short* __restrict__ ch) {
    int gid = blockIdx.x * 256 + threadIdx.x;     // float4 index; 524288 total
    float4 v = ((const float4*)cb)[gid];
    ushort4 hv;
    hv.x = f2bf(v.x); hv.y = f2bf(v.y); hv.z = f2bf(v.z); hv.w = f2bf(v.w);
    ((ushort4*)ch)[gid] = hv;
}

// ---------------- screening GEMM (32x32x16, 2 A-sets, barrier-free) --------
// grid (128 row-tiles, 2 k-splits) x 256 thr (4 waves = 2 rg x 2 cq).
// Block: 128 rows x 4096 codes in 64 tiles of 64 codes (32/wave).
// Two register A-sets (rows rg*32.. and 64+rg*32..) share each B-fragment:
// halves codebook traffic vs 64-row blocks (0.5GB total).
__global__ __launch_bounds__(256, 2)
void gemm_screen32(const unsigned short* __restrict__ zh,
                   const unsigned short* __restrict__ ch,
                   unsigned* __restrict__ cnt, unsigned* __restrict__ cand) {
    __shared__ unsigned rowmax[128];      // fkey of block-local running row max
    __shared__ unsigned cnt_l[128];       // block-local candidate counts
    __shared__ unsigned cand_l[128][LCAP];// packed (score16|code)
    const int tid = threadIdx.x;
    const int l = tid & 63;
    const int wv = tid >> 6;        // 0..3
    const int rg = wv >> 1;         // row-subgroup (0..1)
    const int cq = wv & 1;          // code-half (0..1)
    const int l5 = l >> 5, l31 = l & 31;
    const int n0 = blockIdx.x * 128;
    const int k0 = blockIdx.y * 4096;
    const int toff = (blockIdx.x * 7 + blockIdx.y * 13) & 63;  // decorrelate

    if (tid < 128) { rowmax[tid] = fkey(-3.0e38f); cnt_l[tid] = 0u; }
    __syncthreads();   // init visible (only barrier before flush)

    // Two A-sets: rows n0+rg*32+(0..31) and n0+64+rg*32+(0..31), all 256 d.
    // 32x32x16 A-frag: lane holds A[row=l&31][k = 8*(l>>5) + j]  (HW-verified)
    bf16x8 a0[16], a1[16];
    {
        const unsigned short* zr0 = zh + (size_t)(n0 + rg * 32 + l31) * 256;
        const unsigned short* zr1 = zh + (size_t)(n0 + 64 + rg * 32 + l31) * 256;
#pragma unroll
        for (int k = 0; k < 16; ++k) {
            a0[k] = *(const bf16x8*)(zr0 + k * 16 + l5 * 8);
            a1[k] = *(const bf16x8*)(zr1 + k * 16 + l5 * 8);
        }
    }

    // C/D row mapping: row = base + (r&3) + 8*(r>>2), base = rg*32 + 4*l5
    const int rowb0 = rg * 32 + 4 * l5;
    const int rowb1 = 64 + rowb0;

    float rmc0[16], rmc1[16];   // cached block rowmax (stale-low-safe)
#pragma unroll
    for (int r = 0; r < 16; ++r) { rmc0[r] = -3.0e38f; rmc1[r] = -3.0e38f; }

    for (int t = 0; t < 64; ++t) {
        const int tphys = (t + toff) & 63;
        const int kb = k0 + tphys * 64 + cq * 32;   // this wave's 32 codes
        // B fragments straight from L2: lane reads ch[(kb+l31)*256 + k*16+l5*8]
        const unsigned short* crow = ch + (size_t)(kb + l31) * 256 + l5 * 8;
        bf16x8 bfr[16];
#pragma unroll
        for (int k = 0; k < 16; ++k)
            bfr[k] = *(const bf16x8*)(crow + k * 16);
        f32x16 acc0, acc1;
#pragma unroll
        for (int r = 0; r < 16; ++r) { acc0[r] = 0.f; acc1[r] = 0.f; }
#pragma unroll
        for (int k = 0; k < 16; ++k) {
            acc0 = __builtin_amdgcn_mfma_f32_32x32x16_bf16(a0[k], bfr[k], acc0, 0, 0, 0);
            acc1 = __builtin_amdgcn_mfma_f32_32x32x16_bf16(a1[k], bfr[k], acc1, 0, 0, 0);
        }
        const unsigned code = kb + l31;
        // epilogue: predicated LDS atomicMax (fires only on records) +
        // broadcast re-read -> fresh per-row tau; append packed candidate.
#pragma unroll
        for (int r = 0; r < 16; ++r) {
            int row = rowb0 + (r & 3) + 8 * (r >> 2);
            if (acc0[r] > rmc0[r])
                atomicMax(&rowmax[row], fkey(acc0[r]));           // LDS atomic
            rmc0[r] = funkey(rowmax[row]);                        // broadcast
            if (acc0[r] >= rmc0[r] - MRG_C) {
                unsigned slot = atomicAdd(&cnt_l[row], 1u);       // LDS atomic
                if (slot < LCAP)
                    cand_l[row][slot] = (fkey(acc0[r]) & 0xFFFF0000u) | code;
            }
        }
#pragma unroll
        for (int r = 0; r < 16; ++r) {
            int row = rowb1 + (r & 3) + 8 * (r >> 2);
            if (acc1[r] > rmc1[r])
                atomicMax(&rowmax[row], fkey(acc1[r]));
            rmc1[r] = funkey(rowmax[row]);
            if (acc1[r] >= rmc1[r] - MRG_C) {
                unsigned slot = atomicAdd(&cnt_l[row], 1u);
                if (slot < LCAP)
                    cand_l[row][slot] = (fkey(acc1[r]) & 0xFFFF0000u) | code;
            }
        }
    }

    // flush block-local candidates (one global atomicAdd per row)
    __syncthreads();
    if (tid < 128) {
        unsigned c = cnt_l[tid];
        int n = n0 + tid;
        if (c > LCAP) {
            atomicAdd(&cnt[n], 1000u);        // force exact-scan fallback
        } else if (c > 0) {
            unsigned s0 = atomicAdd(&cnt[n], c);
            for (unsigned i = 0; i < c; ++i)
                if (s0 + i < CAP) cand[n * CAP + s0 + i] = cand_l[tid][i];
        }
    }
}

// ---------------- fused select (score-filtered rescore) + z_q + loss --------
__global__ __launch_bounds__(256)
void select_finalize(const float* __restrict__ z, const float* __restrict__ cb,
                     const float* __restrict__ zn, const unsigned* __restrict__ cnt,
                     const unsigned* __restrict__ cand,
                     float* __restrict__ out) {
    __shared__ float zs[64][257];
    __shared__ int codes_s[64];
    __shared__ float wsum[4];
    const int tid = threadIdx.x;
    const int nbase = blockIdx.x * 64;
    const int b = nbase >> 10, hw0 = nbase & 1023;
    const int lane = tid & 63;
    const int w = tid >> 6;

#pragma unroll 8
    for (int it = 0; it < 64; ++it) {
        int d = it * 4 + w;
        zs[lane][d] = z[(size_t)b * 262144 + (size_t)d * 1024 + hw0 + lane];
    }
    __syncthreads();

#pragma unroll 1
    for (int rr = 0; rr < 16; ++rr) {
        const int ridx = w * 16 + rr;
        const int n = nbase + ridx;
        const unsigned c = cnt[n];
        const float zz = zn[n];
        float bs; int bi;
        if (c > 0 && c <= CAP) {
            // pass 1: screen max from packed keys (u32 max is score-monotone;
            // every wave's running-max records are stored -> max == global)
            unsigned pmax = 0u;
            for (int idx = lane; idx < (int)c; idx += 64)
                pmax = max(pmax, cand[n * CAP + idx]);
#pragma unroll
            for (int m = 1; m <= 32; m <<= 1)
                pmax = max(pmax, (unsigned)__shfl_xor((int)pmax, m));
            const float tauf = funkey(pmax & 0xFFFF0000u) - MRG_SEL;
            // pass 2: exact rescore ONLY candidates within widened margin
            float ss = 3.0e38f; int myk = 0x7fffffff;
            for (int idx = lane; idx < (int)c; idx += 64) {
                unsigned pk = cand[n * CAP + idx];
                if (funkey(pk & 0xFFFF0000u) >= tauf) {
                    int k2 = (int)(pk & 0xFFFFu);
                    const float* cr = cb + (size_t)k2 * 256;
                    float dot = 0.f;
#pragma unroll 8
                    for (int d4 = 0; d4 < 64; ++d4) {   // exact sequential chain
                        float4 cv = ((const float4*)cr)[d4];
                        dot = fmaf(zs[ridx][d4 * 4 + 0], cv.x, dot);
                        dot = fmaf(zs[ridx][d4 * 4 + 1], cv.y, dot);
                        dot = fmaf(zs[ridx][d4 * 4 + 2], cv.z, dot);
                        dot = fmaf(zs[ridx][d4 * 4 + 3], cv.w, dot);
                    }
                    float sc = zz - 2.0f * dot;   // reference score rounding
                    if (sc < ss || (sc == ss && k2 < myk)) { ss = sc; myk = k2; }
                }
            }
            bs = ss; bi = myk;
        } else {
            // overflow/empty fallback: exact full scan (LCAP overflow only)
            bs = 3.0e38f; bi = 0x7fffffff;
            for (int base = 0; base < 8192; base += 64) {
                const float* cr = cb + (size_t)(base + lane) * 256;
                float dot = 0.f;
#pragma unroll 8
                for (int d4 = 0; d4 < 64; ++d4) {
                    float4 cv = ((const float4*)cr)[d4];
                    dot = fmaf(zs[ridx][d4 * 4 + 0], cv.x, dot);
                    dot = fmaf(zs[ridx][d4 * 4 + 1], cv.y, dot);
                    dot = fmaf(zs[ridx][d4 * 4 + 2], cv.z, dot);
                    dot = fmaf(zs[ridx][d4 * 4 + 3], cv.w, dot);
                }
                float sc = zz - 2.0f * dot;
                int k = base + lane;
                if (sc < bs || (sc == bs && k < bi)) { bs = sc; bi = k; }
            }
        }
#pragma unroll
        for (int m = 1; m <= 32; m <<= 1) {
            float ps = __shfl_xor(bs, m);
            int pi = __shfl_xor(bi, m);
            if (ps < bs || (ps == bs && pi < bi)) { bs = ps; bi = pi; }
        }
        if (lane == 0) { codes_s[ridx] = bi; out[4194305 + n] = (float)bi; }
    }
    __syncthreads();

    const int code = codes_s[lane];
    const float* crow = cb + (size_t)code * 256;
    float part = 0.f;
#pragma unroll 8
    for (int j = 0; j < 64; ++j) {
        int d = w * 64 + j;
        float cv = crow[d];
        float ze = zs[lane][d];
        out[(size_t)b * 262144 + (size_t)d * 1024 + hw0 + lane] = cv;
        float diff = ze - cv;
        part += diff * diff;
    }
#pragma unroll
    for (int off = 32; off > 0; off >>= 1) part += __shfl_down(part, off);
    if (lane == 0) wsum[w] = part;
    __syncthreads();
    if (tid == 0) {
        float t = (wsum[0] + wsum[1] + wsum[2] + wsum[3]) * (1.25f / 4194304.f);
        atomicAdd(out + 4194304, t);
    }
}

// ================= fallback path (round-2 kernels, ws-small case) =================
#define NT 128
#define KT 128
#define DC 64
#define KS 4
#define KRANGE (8192 / KS)
#define PSCORE_OFF 32768
#define PIDX_OFF (32768 + KS * 16384)

__global__ __launch_bounds__(256)
void znorm_kernel(const float* __restrict__ z, float* __restrict__ zn) {
    int n = blockIdx.x * 256 + threadIdx.x;
    int b = n >> 10, hw = n & 1023;
    const float* zp = z + (size_t)b * 262144 + hw;
    float s = 0.f;
    for (int d = 0; d < 256; ++d) {
        float v = zp[(size_t)d << 10];
        s += v * v;
    }
    zn[n] = s;
}

__global__ __launch_bounds__(256, 2)
void dist_argmin_kernel(const float* __restrict__ z, const float* __restrict__ cb,
                        const float* __restrict__ zn,
                        float* __restrict__ pscore, int* __restrict__ pidx) {
    __shared__ float zs[DC][NT];
    __shared__ float cs[DC][KT];
    const int tid = threadIdx.x;
    const int tn = tid & 15;
    const int tk = tid >> 4;
    const int n0 = blockIdx.x * NT;
    const int b = n0 >> 10;
    const int hw0 = n0 & 1023;
    const float* zb = z + (size_t)b * 262144 + hw0;
    const int k0base = blockIdx.y * KRANGE;
    float zzr[8];
#pragma unroll
    for (int i = 0; i < 8; ++i) {
        int row = (i < 4) ? (tn * 4 + i) : (64 + tn * 4 + (i - 4));
        zzr[i] = zn[n0 + row];
    }
    float best[8]; int bidx[8];
#pragma unroll
    for (int i = 0; i < 8; ++i) { best[i] = 3.0e38f; bidx[i] = 0; }
    for (int kt = 0; kt < KRANGE / KT; ++kt) {
        const int k0 = k0base + kt * KT;
        float acc[8][8];
#pragma unroll
        for (int i = 0; i < 8; ++i)
#pragma unroll
            for (int j = 0; j < 8; ++j) acc[i][j] = 0.f;
        for (int dc = 0; dc < 256; dc += DC) {
            __syncthreads();
#pragma unroll
            for (int it = 0; it < 8; ++it) {
                int idx = it * 256 + tid;
                int d = idx >> 5, nv = idx & 31;
                float4 v = *(const float4*)(zb + (size_t)(dc + d) * 1024 + nv * 4);
                *(float4*)&zs[d][nv * 4] = v;
            }
#pragma unroll
            for (int it = 0; it < 8; ++it) {
                int idx = it * 256 + tid;
                int k = idx >> 4, dv = idx & 15;
                float4 v = *(const float4*)(cb + (size_t)(k0 + k) * 256 + dc + dv * 4);
                int colv = k ^ ((dv & 7) << 2);
                cs[dv * 4 + 0][colv] = v.x;
                cs[dv * 4 + 1][colv] = v.y;
                cs[dv * 4 + 2][colv] = v.z;
                cs[dv * 4 + 3][colv] = v.w;
            }
            __syncthreads();
#pragma unroll 2
            for (int d = 0; d < DC; ++d) {
                int swz = ((d >> 2) & 7) << 2;
                float4 a0 = *(const float4*)&zs[d][tn * 4];
                float4 a1 = *(const float4*)&zs[d][64 + tn * 4];
                float4 b0 = *(const float4*)&cs[d][(tk * 4) ^ swz];
                float4 b1 = *(const float4*)&cs[d][(64 + tk * 4) ^ swz];
                float av[8] = {a0.x, a0.y, a0.z, a0.w, a1.x, a1.y, a1.z, a1.w};
                float bv[8] = {b0.x, b0.y, b0.z, b0.w, b1.x, b1.y, b1.z, b1.w};
#pragma unroll
                for (int i = 0; i < 8; ++i)
#pragma unroll
                    for (int j = 0; j < 8; ++j)
                        acc[i][j] = fmaf(av[i], bv[j], acc[i][j]);
            }
        }
#pragma unroll
        for (int j = 0; j < 8; ++j) {
            int kloc = (j < 4) ? (tk * 4 + j) : (64 + tk * 4 + (j - 4));
            int kk = k0 + kloc;
#pragma unroll
            for (int i = 0; i < 8; ++i) {
                float s = zzr[i] - 2.0f * acc[i][j];
                if (s < best[i]) { best[i] = s; bidx[i] = kk; }
            }
        }
    }
    __syncthreads();
    float* sredf = &zs[0][0];
    int* sredi = (int*)&cs[0][0];
#pragma unroll
    for (int i = 0; i < 8; ++i) {
        int row = (i < 4) ? (tn * 4 + i) : (64 + tn * 4 + (i - 4));
        sredf[row * 16 + tk] = best[i];
        sredi[row * 16 + tk] = bidx[i];
    }
    __syncthreads();
    if (tid < NT) {
        float bs = sredf[tid * 16];
        int bi = sredi[tid * 16];
#pragma unroll
        for (int t = 1; t < 16; ++t) {
            float s = sredf[tid * 16 + t];
            int ix = sredi[tid * 16 + t];
            if (s < bs || (s == bs && ix < bi)) { bs = s; bi = ix; }
        }
        pscore[blockIdx.y * 16384 + n0 + tid] = bs;
        pidx[blockIdx.y * 16384 + n0 + tid] = bi;
    }
}

__global__ __launch_bounds__(256)
void finalize_kernel(const float* __restrict__ z, const float* __restrict__ cb,
                     const float* __restrict__ pscore, const int* __restrict__ pidx,
                     float* __restrict__ out) {
    __shared__ int codes_s[64];
    __shared__ float wsum[4];
    const int nbase = blockIdx.x * 64;
    const int tid = threadIdx.x;
    if (tid < 64) {
        int n = nbase + tid;
        float bs = pscore[n];
        int bi = pidx[n];
#pragma unroll
        for (int p = 1; p < KS; ++p) {
            float s = pscore[p * 16384 + n];
            int ix = pidx[p * 16384 + n];
            if (s < bs || (s == bs && ix < bi)) { bs = s; bi = ix; }
        }
        codes_s[tid] = bi;
        out[4194305 + n] = (float)bi;
    }
    __syncthreads();
    const int lane = tid & 63;
    const int w = tid >> 6;
    const int n = nbase + lane;
    const int b = n >> 10, hw = n & 1023;
    const int code = codes_s[lane];
    const float* crow = cb + (size_t)code * 256;
    const float* zrow = z + (size_t)b * 262144 + hw;
    float* orow = out + (size_t)b * 262144 + hw;
    float part = 0.f;
    for (int j = 0; j < 64; ++j) {
        int d = w * 64 + j;
        float cv = crow[d];
        float ze = zrow[(size_t)d * 1024];
        orow[(size_t)d * 1024] = cv;
        float diff = ze - cv;
        part += diff * diff;
    }
#pragma unroll
    for (int off = 32; off > 0; off >>= 1) part += __shfl_down(part, off);
    if (lane == 0) wsum[w] = part;
    __syncthreads();
    if (tid == 0) {
        float t = (wsum[0] + wsum[1] + wsum[2] + wsum[3]) * (1.25f / 4194304.f);
        atomicAdd(out + 4194304, t);
    }
}

// ================= launcher =================
extern "C" void kernel_launch(void* const* d_in, const int* in_sizes, int n_in,
                              void* d_out, int out_size, void* d_ws, size_t ws_size,
                              hipStream_t stream) {
    const float* z = (const float*)d_in[0];
    const float* cb = (const float*)d_in[1];
    float* out = (float*)d_out;
    char* wsb = (char*)d_ws;

    if (ws_size >= WS_NEED) {
        float* zn = (float*)(wsb + ZN_B);
        unsigned* cnt = (unsigned*)(wsb + CNT_B);
        unsigned* cand = (unsigned*)(wsb + CAND_B);
        unsigned short* zh = (unsigned short*)(wsb + ZH_B);
        unsigned short* ch = (unsigned short*)(wsb + CH_B);

        hipMemsetAsync(wsb + CNT_B, 0, 65536, stream);
        hipMemsetAsync(out + 4194304, 0, sizeof(float), stream);

        prep_z_kernel<<<256, 256, 0, stream>>>(z, zn, zh);
        split_c_kernel<<<2048, 256, 0, stream>>>(cb, ch);
        gemm_screen32<<<dim3(128, 2), 256, 0, stream>>>(zh, ch, cnt, cand);
        select_finalize<<<256, 256, 0, stream>>>(z, cb, zn, cnt, cand, out);
    } else {
        float* zn = (float*)wsb;
        float* pscore = (float*)wsb + PSCORE_OFF;
        int* pidx = (int*)((float*)wsb + PIDX_OFF);
        znorm_kernel<<<64, 256, 0, stream>>>(z, zn);
        dim3 grid(16384 / NT, KS);
        dist_argmin_kernel<<<grid, 256, 0, stream>>>(z, cb, zn, pscore, pidx);
        hipMemsetAsync(out + 4194304, 0, sizeof(float), stream);
        finalize_kernel<<<16384 / 64, 256, 0, stream>>>(z, cb, pscore, pidx, out);
    }
}